// Round 1
// 1187.746 us; speedup vs baseline: 1.4312x; 1.4312x over previous
//
#include <hip/hip_runtime.h>
#include <cstdint>
#include <cstddef>

#define N_NODES 100000
#define N_EDGES 1600000
// D_NODE=256, D_MSG=128, D_RBF=32, H=8, D_HEAD=16

#define M_PAD 100096   // 782*128
#define SCAN_NB 98     // ceil(N_NODES/1024)
#define CH 32          // edges per LDS chunk in k_node

// ---- workspace layout (float offsets) ----
// XLR:    N*256 f32                      [xl | xr]
// XB:     M_PAD*256 bf16 (padded x)      = 12,812,288 floats
// ACCB:   M_PAD*128 bf16 (edge output)   =  6,406,144 floats
// CSRS:   E int (src per CSR slot)
// CSRE:   E int (edge id per CSR slot)
// ROW:    N+1 int (CSR row offsets)
// CNT:    N int (scatter cursors)
// DEGI:   N int (histogram)
// BSUMS:  128 int
// BCAT/WCOMBT/WCATB/WM2NB: folded weights
#define OFF_XLR    ((size_t)0)
#define OFF_XB     (OFF_XLR    + (size_t)N_NODES*256)      // 25,600,000
#define OFF_ACCB   (OFF_XB     + (size_t)12812288)         // 38,412,288
#define OFF_CSRS   (OFF_ACCB   + (size_t)6406144)          // 44,818,432
#define OFF_CSRE   (OFF_CSRS   + (size_t)N_EDGES)          // 46,418,432
#define OFF_ROW    (OFF_CSRE   + (size_t)N_EDGES)          // 48,018,432
#define OFF_CNT    (OFF_ROW    + (size_t)100016)           // 48,118,448
#define OFF_DEGI   (OFF_CNT    + (size_t)N_NODES)          // 48,218,448
#define OFF_BSUMS  (OFF_DEGI   + (size_t)N_NODES)          // 48,318,448
#define OFF_BCAT   (OFF_BSUMS  + 128)
#define OFF_WCOMBT (OFF_BCAT   + 256)
#define OFF_WCATB  (OFF_WCOMBT + 4096)
#define OFF_WM2NB  (OFF_WCATB  + 32768)
// total = 48,372,080 floats = 193.5 MB (< previous 224.7 MB budget)

typedef __attribute__((ext_vector_type(8))) short short8;
typedef __attribute__((ext_vector_type(4))) float float4v;

__device__ __forceinline__ unsigned short f2bf(float f) {
  unsigned u = __float_as_uint(f);
  unsigned r = (u + 0x7fff + ((u >> 16) & 1)) >> 16;
  return (unsigned short)r;
}

// ---------------- zero-init (float4 granularity) ----------------
__global__ void k_zero(float* __restrict__ p, size_t n4) {
  size_t i = (size_t)blockIdx.x * blockDim.x + threadIdx.x;
  size_t stride = (size_t)gridDim.x * blockDim.x;
  float4 z = make_float4(0.f, 0.f, 0.f, 0.f);
  for (; i < n4; i += stride) ((float4*)p)[i] = z;
}

// ---------------- f32 -> bf16 convert ----------------
__global__ void k_convx(const float* __restrict__ x, unsigned short* __restrict__ xb, unsigned n4) {
  unsigned i = blockIdx.x * blockDim.x + threadIdx.x;
  unsigned stride = gridDim.x * blockDim.x;
  for (; i < n4; i += stride) {
    float4 v = ((const float4*)x)[i];
    ushort4 o;
    o.x = f2bf(v.x); o.y = f2bf(v.y); o.z = f2bf(v.z); o.w = f2bf(v.w);
    ((ushort4*)xb)[i] = o;
  }
}

// ---------------- fold weights ----------------
__global__ void k_weights(const float* __restrict__ Wl, const float* __restrict__ Wr,
                          const float* __restrict__ We, const float* __restrict__ W_n2m,
                          const float* __restrict__ W_r2m, const float* __restrict__ bl,
                          const float* __restrict__ br, const float* __restrict__ W_m2n,
                          unsigned short* __restrict__ WcatB, float* __restrict__ bcat,
                          float* __restrict__ WcombT, unsigned short* __restrict__ Wm2nB) {
  int idx = blockIdx.x * blockDim.x + threadIdx.x;
  if (idx < 65536) {
    int o = idx >> 8, i = idx & 255;
    const float* wrow = (o < 128) ? (Wl + o * 128) : (Wr + (o - 128) * 128);
    float s = 0.f;
    for (int k = 0; k < 128; ++k) s += wrow[k] * W_n2m[k * 256 + i];
    WcatB[idx] = f2bf(s);
  } else if (idx < 65536 + 256) {
    int o = idx - 65536;
    bcat[o] = (o < 128) ? bl[o] : br[o - 128];
  } else if (idx < 65536 + 256 + 4096) {
    int q = idx - (65536 + 256);
    int j = q >> 7, o = q & 127;
    float s = 0.f;
    for (int k = 0; k < 128; ++k) s += We[o * 128 + k] * W_r2m[k * 32 + j];
    WcombT[q] = s;
  } else if (idx < 65536 + 256 + 4096 + 32768) {
    int q = idx - (65536 + 256 + 4096);
    Wm2nB[q] = f2bf(W_m2n[q]);
  }
}

// ---------------- bf16 MFMA GEMM: C[M][NC] = A[M][K] @ B[NC][K]^T (+bias) ----------------
template <bool HAS_BIAS>
__global__ __launch_bounds__(256) void gemm_mfma(const unsigned short* __restrict__ A,
                                                 const unsigned short* __restrict__ B,
                                                 const float* __restrict__ bias,
                                                 float* __restrict__ C,
                                                 int M, int NC, int K) {
  __shared__ short As[128 * 32];
  __shared__ short Bs[128 * 32];
  const int tid = threadIdx.x;
  const int lane = tid & 63;
  const int wv = tid >> 6;
  const int rowBase = blockIdx.x << 7;
  const int colBase = blockIdx.y << 7;
  const int wrow = (wv & 1) << 6;
  const int wcol = (wv >> 1) << 6;

  const int srow = tid >> 2;
  const int skc = (tid & 3) << 3;

  const int n0 = lane & 15;
  const int q = lane >> 4;

  float4v acc[4][4];
#pragma unroll
  for (int i = 0; i < 4; ++i)
#pragma unroll
    for (int j = 0; j < 4; ++j) acc[i][j] = (float4v)(0.f);

  for (int k0 = 0; k0 < K; k0 += 32) {
    const unsigned aoff0 = (unsigned)(rowBase + srow) * K + k0 + skc;
    const unsigned aoff1 = (unsigned)(rowBase + 64 + srow) * K + k0 + skc;
    const unsigned boff0 = (unsigned)(colBase + srow) * K + k0 + skc;
    const unsigned boff1 = (unsigned)(colBase + 64 + srow) * K + k0 + skc;
    uint4 a0 = *(const uint4*)(A + aoff0);
    uint4 a1 = *(const uint4*)(A + aoff1);
    uint4 b0 = *(const uint4*)(B + boff0);
    uint4 b1 = *(const uint4*)(B + boff1);
    __syncthreads();
    ((uint4*)As)[tid] = a0;
    ((uint4*)As)[256 + tid] = a1;
    ((uint4*)Bs)[tid] = b0;
    ((uint4*)Bs)[256 + tid] = b1;
    __syncthreads();

    short8 af[4], bf[4];
    const short8* Ap = (const short8*)As;
    const short8* Bp = (const short8*)Bs;
#pragma unroll
    for (int i = 0; i < 4; ++i) af[i] = Ap[(wrow + i * 16 + n0) * 4 + q];
#pragma unroll
    for (int j = 0; j < 4; ++j) bf[j] = Bp[(wcol + j * 16 + n0) * 4 + q];
#pragma unroll
    for (int i = 0; i < 4; ++i)
#pragma unroll
      for (int j = 0; j < 4; ++j)
        acc[i][j] = __builtin_amdgcn_mfma_f32_16x16x32_bf16(af[i], bf[j], acc[i][j], 0, 0, 0);
  }

#pragma unroll
  for (int j = 0; j < 4; ++j) {
    const int col = colBase + wcol + j * 16 + n0;
    const float bv = HAS_BIAS ? bias[col] : 0.f;
#pragma unroll
    for (int i = 0; i < 4; ++i) {
      const int row0 = rowBase + wrow + i * 16 + (q << 2);
#pragma unroll
      for (int r = 0; r < 4; ++r) {
        const int row = row0 + r;
        if (row < M) C[(unsigned)row * NC + col] = acc[i][j][r] + bv;
      }
    }
  }
}

// ---------------- CSR build: histogram ----------------
__global__ void k_hist(const int* __restrict__ dst, int* __restrict__ degi) {
  unsigned e = blockIdx.x * blockDim.x + threadIdx.x;
  if (e < N_EDGES) atomicAdd(&degi[dst[e]], 1);
}

// ---------------- CSR build: scan (3 kernels) ----------------
__global__ __launch_bounds__(1024) void k_scan1(const int* __restrict__ degi,
                                                int* __restrict__ row,
                                                int* __restrict__ bsums) {
  __shared__ int sm[1024];
  const int tid = threadIdx.x;
  const unsigned i = blockIdx.x * 1024 + tid;
  int v = (i < N_NODES) ? degi[i] : 0;
  sm[tid] = v;
  __syncthreads();
  for (int d = 1; d < 1024; d <<= 1) {
    int t = (tid >= d) ? sm[tid - d] : 0;
    __syncthreads();
    sm[tid] += t;
    __syncthreads();
  }
  int incl = sm[tid];
  if (i < N_NODES) row[i] = incl - v;  // exclusive within block
  if (tid == 1023) bsums[blockIdx.x] = incl;
}

__global__ void k_scan2(int* __restrict__ bsums) {
  __shared__ int sm[SCAN_NB];
  const int tid = threadIdx.x;
  if (tid < SCAN_NB) sm[tid] = bsums[tid];
  __syncthreads();
  if (tid == 0) {
    int run = 0;
    for (int b = 0; b < SCAN_NB; ++b) { int t = sm[b]; sm[b] = run; run += t; }
  }
  __syncthreads();
  if (tid < SCAN_NB) bsums[tid] = sm[tid];
}

__global__ __launch_bounds__(1024) void k_scan3(int* __restrict__ row,
                                                const int* __restrict__ bsums) {
  const unsigned i = blockIdx.x * 1024 + threadIdx.x;
  if (i < N_NODES) row[i] += bsums[blockIdx.x];
  if (i == 0) row[N_NODES] = N_EDGES;
}

// ---------------- CSR build: scatter edges into rows ----------------
__global__ void k_scatter(const int* __restrict__ src, const int* __restrict__ dst,
                          const int* __restrict__ row, int* __restrict__ cnt,
                          int* __restrict__ csrs, int* __restrict__ csre) {
  unsigned e = blockIdx.x * blockDim.x + threadIdx.x;
  if (e < N_EDGES) {
    int d = dst[e];
    int pos = row[d] + atomicAdd(&cnt[d], 1);
    csrs[pos] = src[e];
    csre[pos] = (int)e;
  }
}

// ---------------- fused per-node edge phase ----------------
// One block (128 thr) per destination node. Single pass over incoming edges:
//   et = rbf[e] . WcombT           (per channel)
//   u  = leaky(xl[src] + xr[d] + et);  logit r = sum_{16 lanes} u*att
//   p  = exp(r);  den += p;  S += p * xl[src];  rbfacc += rbf[e]
// Then self-loop (mean rbf), out = S/den + bias -> bf16.
// No atomics, no materialized p/denom/acc.
__global__ __launch_bounds__(128) void k_node(
    const float* __restrict__ XLR, const float* __restrict__ rbf,
    const int* __restrict__ csrs, const int* __restrict__ csre,
    const int* __restrict__ row, const float* __restrict__ WcombT,
    const float* __restrict__ att, const float* __restrict__ bias,
    unsigned short* __restrict__ accb) {
  __shared__ __align__(16) float rbf_s[CH][32];
  __shared__ int src_s[CH];
  __shared__ int eid_s[CH];
  __shared__ __align__(16) float rbfs_l[32];
  const int tid = threadIdx.x;
  const unsigned n = blockIdx.x;

  float wreg[32];
#pragma unroll
  for (int j = 0; j < 32; ++j) wreg[j] = WcombT[j * 128 + tid];
  const float att_r = att[tid];

  const int off = row[n], end = row[n + 1];
  const float xl_d = XLR[(n << 8) + tid];
  const float xr_d = XLR[(n << 8) + 128 + tid];

  float S = 0.f, den = 0.f;
  float rbfacc = 0.f;  // meaningful for tid < 32

  for (int c0 = off; c0 < end; c0 += CH) {
    const int cnt = min(CH, end - c0);
    __syncthreads();  // protect LDS reuse vs previous chunk readers
    if (tid < cnt) { src_s[tid] = csrs[c0 + tid]; eid_s[tid] = csre[c0 + tid]; }
    __syncthreads();
    for (int idx = tid; idx < cnt * 32; idx += 128)
      rbf_s[idx >> 5][idx & 31] = rbf[(size_t)(unsigned)eid_s[idx >> 5] * 32 + (idx & 31)];
    __syncthreads();
#pragma unroll 2
    for (int i = 0; i < cnt; ++i) {
      const unsigned s = (unsigned)src_s[i];
      const float4* r4 = (const float4*)rbf_s[i];
      float et = 0.f;
#pragma unroll
      for (int j4 = 0; j4 < 8; ++j4) {
        float4 rv = r4[j4];
        et += rv.x * wreg[j4 * 4 + 0] + rv.y * wreg[j4 * 4 + 1] +
              rv.z * wreg[j4 * 4 + 2] + rv.w * wreg[j4 * 4 + 3];
      }
      const float xls = XLR[(s << 8) + tid];
      float u = xls + xr_d + et;
      u = (u > 0.f) ? u : 0.2f * u;
      float r = u * att_r;
      r += __shfl_xor(r, 1);
      r += __shfl_xor(r, 2);
      r += __shfl_xor(r, 4);
      r += __shfl_xor(r, 8);
      const float p = __expf(r);
      den += p;
      S += p * xls;
      if (tid < 32) rbfacc += rbf_s[i][tid];
    }
  }

  // self-loop: et from mean of incoming rbf
  __syncthreads();
  if (tid < 32) rbfs_l[tid] = rbfacc;
  __syncthreads();
  const float inv = 1.f / fmaxf((float)(end - off), 1.f);
  float et = 0.f;
  {
    const float4* r4 = (const float4*)rbfs_l;
#pragma unroll
    for (int j4 = 0; j4 < 8; ++j4) {
      float4 rv = r4[j4];
      et += rv.x * wreg[j4 * 4 + 0] + rv.y * wreg[j4 * 4 + 1] +
            rv.z * wreg[j4 * 4 + 2] + rv.w * wreg[j4 * 4 + 3];
    }
  }
  et *= inv;
  float u = xl_d + xr_d + et;
  u = (u > 0.f) ? u : 0.2f * u;
  float r = u * att_r;
  r += __shfl_xor(r, 1);
  r += __shfl_xor(r, 2);
  r += __shfl_xor(r, 4);
  r += __shfl_xor(r, 8);
  const float p = __expf(r);
  den += p;
  S += p * xl_d;

  const float outv = S / den + bias[tid];
  accb[((size_t)n << 7) + tid] = f2bf(outv);
}

extern "C" void kernel_launch(void* const* d_in, const int* in_sizes, int n_in,
                              void* d_out, int out_size, void* d_ws, size_t ws_size,
                              hipStream_t stream) {
  const float* x     = (const float*)d_in[0];
  const float* rbf   = (const float*)d_in[1];
  const int*   ei    = (const int*)d_in[2];
  const float* W_n2m = (const float*)d_in[4];
  const float* W_r2m = (const float*)d_in[5];
  const float* Wl    = (const float*)d_in[6];
  const float* bl    = (const float*)d_in[7];
  const float* Wr    = (const float*)d_in[8];
  const float* br    = (const float*)d_in[9];
  const float* We    = (const float*)d_in[10];
  const float* att   = (const float*)d_in[11];
  const float* bias  = (const float*)d_in[12];
  const float* W_m2n = (const float*)d_in[13];
  float* out = (float*)d_out;
  float* ws  = (float*)d_ws;

  const int* src = ei;
  const int* dst = ei + N_EDGES;

  float* XLR    = ws + OFF_XLR;
  unsigned short* xb    = (unsigned short*)(ws + OFF_XB);
  unsigned short* accb  = (unsigned short*)(ws + OFF_ACCB);
  int* csrs   = (int*)(ws + OFF_CSRS);
  int* csre   = (int*)(ws + OFF_CSRE);
  int* rowoff = (int*)(ws + OFF_ROW);
  int* cnt    = (int*)(ws + OFF_CNT);
  int* degi   = (int*)(ws + OFF_DEGI);
  int* bsums  = (int*)(ws + OFF_BSUMS);
  float* bcat   = ws + OFF_BCAT;
  float* WcombT = ws + OFF_WCOMBT;
  unsigned short* WcatB = (unsigned short*)(ws + OFF_WCATB);
  unsigned short* Wm2nB = (unsigned short*)(ws + OFF_WM2NB);

  // 1. fold weights (+ bf16 conversions)
  k_weights<<<401, 256, 0, stream>>>(Wl, Wr, We, W_n2m, W_r2m, bl, br, W_m2n,
                                     WcatB, bcat, WcombT, Wm2nB);
  // 2. x -> bf16
  k_convx<<<2048, 256, 0, stream>>>(x, xb, (unsigned)(N_NODES * 256 / 4));
  // 3. XLR = x @ [Wl@W_n2m ; Wr@W_n2m]^T + [bl|br]   (bf16 MFMA)
  gemm_mfma<true><<<dim3(M_PAD / 128, 2), 256, 0, stream>>>(
      xb, WcatB, bcat, XLR, N_NODES, 256, 256);
  // 4. CSR build: zero cnt+degi (contiguous 200,000 ints), hist, scan, scatter
  k_zero<<<196, 256, 0, stream>>>(ws + OFF_CNT, 50000);
  k_hist<<<N_EDGES / 256, 256, 0, stream>>>(dst, degi);
  k_scan1<<<SCAN_NB, 1024, 0, stream>>>(degi, rowoff, bsums);
  k_scan2<<<1, 128, 0, stream>>>(bsums);
  k_scan3<<<SCAN_NB, 1024, 0, stream>>>(rowoff, bsums);
  k_scatter<<<N_EDGES / 256, 256, 0, stream>>>(src, dst, rowoff, cnt, csrs, csre);
  // 5. fused edge phase: one block per node, no atomics, writes bf16 directly
  k_node<<<N_NODES, 128, 0, stream>>>(XLR, rbf, csrs, csre, rowoff, WcombT,
                                      att, bias, accb);
  // 6. out = acc @ W_m2n^T  (bf16 MFMA)
  gemm_mfma<false><<<dim3(M_PAD / 128, 2), 256, 0, stream>>>(
      accb, Wm2nB, nullptr, out, N_NODES, 256, 128);
}

// Round 2
// 965.337 us; speedup vs baseline: 1.7610x; 1.2304x over previous
//
#include <hip/hip_runtime.h>
#include <cstdint>
#include <cstddef>

#define N_NODES 100000
#define N_EDGES 1600000
// D_NODE=256, D_MSG=128, D_RBF=32, H=8, D_HEAD=16

#define M_PAD 100096   // 782*128
#define SCAN_NB 98     // ceil(N_NODES/1024)
#define CH 16          // CSR slots per chunk in k_node (matches MFMA M=16)

// ---- workspace layout (float offsets) ----
// XLR:    N*256 f32                      [xl | xr]
// XB:     M_PAD*256 bf16 (padded x)      = 12,812,288 floats
// ACCB:   M_PAD*128 bf16 (edge output)   =  6,406,144 floats
// CSRS:   E int (src per CSR slot)
// CSRE:   E int (edge id per CSR slot)
// ROW:    N+1 int (CSR row offsets)
// CNT:    N int (scatter cursors)
// DEGI:   N int (histogram)
// BSUMS:  128 int
// BCAT/WCOMBB/WCATB/WM2NB: folded weights
#define OFF_XLR    ((size_t)0)
#define OFF_XB     (OFF_XLR    + (size_t)N_NODES*256)      // 25,600,000
#define OFF_ACCB   (OFF_XB     + (size_t)12812288)         // 38,412,288
#define OFF_CSRS   (OFF_ACCB   + (size_t)6406144)          // 44,818,432
#define OFF_CSRE   (OFF_CSRS   + (size_t)N_EDGES)          // 46,418,432
#define OFF_ROW    (OFF_CSRE   + (size_t)N_EDGES)          // 48,018,432
#define OFF_CNT    (OFF_ROW    + (size_t)100016)           // 48,118,448
#define OFF_DEGI   (OFF_CNT    + (size_t)N_NODES)          // 48,218,448
#define OFF_BSUMS  (OFF_DEGI   + (size_t)N_NODES)          // 48,318,448
#define OFF_BCAT   (OFF_BSUMS  + 128)
#define OFF_WCOMBB (OFF_BCAT   + 256)                      // 2048 floats = 4096 bf16
#define OFF_WCATB  (OFF_WCOMBB + 2048)
#define OFF_WM2NB  (OFF_WCATB  + 32768)
// total ~= 48,370,032 floats = 193.5 MB

typedef __attribute__((ext_vector_type(8))) short short8;
typedef __attribute__((ext_vector_type(4))) float float4v;

__device__ __forceinline__ unsigned short f2bf(float f) {
  unsigned u = __float_as_uint(f);
  unsigned r = (u + 0x7fff + ((u >> 16) & 1)) >> 16;
  return (unsigned short)r;
}

// ---------------- zero-init (float4 granularity) ----------------
__global__ void k_zero(float* __restrict__ p, size_t n4) {
  size_t i = (size_t)blockIdx.x * blockDim.x + threadIdx.x;
  size_t stride = (size_t)gridDim.x * blockDim.x;
  float4 z = make_float4(0.f, 0.f, 0.f, 0.f);
  for (; i < n4; i += stride) ((float4*)p)[i] = z;
}

// ---------------- f32 -> bf16 convert ----------------
__global__ void k_convx(const float* __restrict__ x, unsigned short* __restrict__ xb, unsigned n4) {
  unsigned i = blockIdx.x * blockDim.x + threadIdx.x;
  unsigned stride = gridDim.x * blockDim.x;
  for (; i < n4; i += stride) {
    float4 v = ((const float4*)x)[i];
    ushort4 o;
    o.x = f2bf(v.x); o.y = f2bf(v.y); o.z = f2bf(v.z); o.w = f2bf(v.w);
    ((ushort4*)xb)[i] = o;
  }
}

// ---------------- fold weights ----------------
// WcatB  [256][256] bf16 : rows = [Wl;Wr] @ W_n2m
// bcat   [256] f32       : [bl|br]
// WcombB [128][32] bf16  : Wcomb[o][j] = sum_m We[o][m] * W_r2m[m][j]
// Wm2nB  [256][128] bf16 : W_m2n
__global__ void k_weights(const float* __restrict__ Wl, const float* __restrict__ Wr,
                          const float* __restrict__ We, const float* __restrict__ W_n2m,
                          const float* __restrict__ W_r2m, const float* __restrict__ bl,
                          const float* __restrict__ br, const float* __restrict__ W_m2n,
                          unsigned short* __restrict__ WcatB, float* __restrict__ bcat,
                          unsigned short* __restrict__ WcombB, unsigned short* __restrict__ Wm2nB) {
  int idx = blockIdx.x * blockDim.x + threadIdx.x;
  if (idx < 65536) {
    int o = idx >> 8, i = idx & 255;
    const float* wrow = (o < 128) ? (Wl + o * 128) : (Wr + (o - 128) * 128);
    float s = 0.f;
    for (int k = 0; k < 128; ++k) s += wrow[k] * W_n2m[k * 256 + i];
    WcatB[idx] = f2bf(s);
  } else if (idx < 65536 + 256) {
    int o = idx - 65536;
    bcat[o] = (o < 128) ? bl[o] : br[o - 128];
  } else if (idx < 65536 + 256 + 4096) {
    int q = idx - (65536 + 256);
    int j = q >> 7, o = q & 127;
    float s = 0.f;
    for (int k = 0; k < 128; ++k) s += We[o * 128 + k] * W_r2m[k * 32 + j];
    WcombB[o * 32 + j] = f2bf(s);
  } else if (idx < 65536 + 256 + 4096 + 32768) {
    int q = idx - (65536 + 256 + 4096);
    Wm2nB[q] = f2bf(W_m2n[q]);
  }
}

// ---------------- bf16 MFMA GEMM: C[M][NC] = A[M][K] @ B[NC][K]^T (+bias) ----------------
template <bool HAS_BIAS>
__global__ __launch_bounds__(256) void gemm_mfma(const unsigned short* __restrict__ A,
                                                 const unsigned short* __restrict__ B,
                                                 const float* __restrict__ bias,
                                                 float* __restrict__ C,
                                                 int M, int NC, int K) {
  __shared__ short As[128 * 32];
  __shared__ short Bs[128 * 32];
  const int tid = threadIdx.x;
  const int lane = tid & 63;
  const int wv = tid >> 6;
  const int rowBase = blockIdx.x << 7;
  const int colBase = blockIdx.y << 7;
  const int wrow = (wv & 1) << 6;
  const int wcol = (wv >> 1) << 6;

  const int srow = tid >> 2;
  const int skc = (tid & 3) << 3;

  const int n0 = lane & 15;
  const int q = lane >> 4;

  float4v acc[4][4];
#pragma unroll
  for (int i = 0; i < 4; ++i)
#pragma unroll
    for (int j = 0; j < 4; ++j) acc[i][j] = (float4v)(0.f);

  for (int k0 = 0; k0 < K; k0 += 32) {
    const unsigned aoff0 = (unsigned)(rowBase + srow) * K + k0 + skc;
    const unsigned aoff1 = (unsigned)(rowBase + 64 + srow) * K + k0 + skc;
    const unsigned boff0 = (unsigned)(colBase + srow) * K + k0 + skc;
    const unsigned boff1 = (unsigned)(colBase + 64 + srow) * K + k0 + skc;
    uint4 a0 = *(const uint4*)(A + aoff0);
    uint4 a1 = *(const uint4*)(A + aoff1);
    uint4 b0 = *(const uint4*)(B + boff0);
    uint4 b1 = *(const uint4*)(B + boff1);
    __syncthreads();
    ((uint4*)As)[tid] = a0;
    ((uint4*)As)[256 + tid] = a1;
    ((uint4*)Bs)[tid] = b0;
    ((uint4*)Bs)[256 + tid] = b1;
    __syncthreads();

    short8 af[4], bf[4];
    const short8* Ap = (const short8*)As;
    const short8* Bp = (const short8*)Bs;
#pragma unroll
    for (int i = 0; i < 4; ++i) af[i] = Ap[(wrow + i * 16 + n0) * 4 + q];
#pragma unroll
    for (int j = 0; j < 4; ++j) bf[j] = Bp[(wcol + j * 16 + n0) * 4 + q];
#pragma unroll
    for (int i = 0; i < 4; ++i)
#pragma unroll
      for (int j = 0; j < 4; ++j)
        acc[i][j] = __builtin_amdgcn_mfma_f32_16x16x32_bf16(af[i], bf[j], acc[i][j], 0, 0, 0);
  }

#pragma unroll
  for (int j = 0; j < 4; ++j) {
    const int col = colBase + wcol + j * 16 + n0;
    const float bv = HAS_BIAS ? bias[col] : 0.f;
#pragma unroll
    for (int i = 0; i < 4; ++i) {
      const int row0 = rowBase + wrow + i * 16 + (q << 2);
#pragma unroll
      for (int r = 0; r < 4; ++r) {
        const int row = row0 + r;
        if (row < M) C[(unsigned)row * NC + col] = acc[i][j][r] + bv;
      }
    }
  }
}

// ---------------- CSR build: histogram ----------------
__global__ void k_hist(const int* __restrict__ dst, int* __restrict__ degi) {
  unsigned e = blockIdx.x * blockDim.x + threadIdx.x;
  if (e < N_EDGES) atomicAdd(&degi[dst[e]], 1);
}

// ---------------- CSR build: scan (3 kernels) ----------------
__global__ __launch_bounds__(1024) void k_scan1(const int* __restrict__ degi,
                                                int* __restrict__ row,
                                                int* __restrict__ bsums) {
  __shared__ int sm[1024];
  const int tid = threadIdx.x;
  const unsigned i = blockIdx.x * 1024 + tid;
  int v = (i < N_NODES) ? degi[i] : 0;
  sm[tid] = v;
  __syncthreads();
  for (int d = 1; d < 1024; d <<= 1) {
    int t = (tid >= d) ? sm[tid - d] : 0;
    __syncthreads();
    sm[tid] += t;
    __syncthreads();
  }
  int incl = sm[tid];
  if (i < N_NODES) row[i] = incl - v;  // exclusive within block
  if (tid == 1023) bsums[blockIdx.x] = incl;
}

__global__ void k_scan2(int* __restrict__ bsums) {
  __shared__ int sm[SCAN_NB];
  const int tid = threadIdx.x;
  if (tid < SCAN_NB) sm[tid] = bsums[tid];
  __syncthreads();
  if (tid == 0) {
    int run = 0;
    for (int b = 0; b < SCAN_NB; ++b) { int t = sm[b]; sm[b] = run; run += t; }
  }
  __syncthreads();
  if (tid < SCAN_NB) bsums[tid] = sm[tid];
}

__global__ __launch_bounds__(1024) void k_scan3(int* __restrict__ row,
                                                const int* __restrict__ bsums) {
  const unsigned i = blockIdx.x * 1024 + threadIdx.x;
  if (i < N_NODES) row[i] += bsums[blockIdx.x];
  if (i == 0) row[N_NODES] = N_EDGES;
}

// ---------------- CSR build: scatter edges into rows ----------------
__global__ void k_scatter(const int* __restrict__ src, const int* __restrict__ dst,
                          const int* __restrict__ row, int* __restrict__ cnt,
                          int* __restrict__ csrs, int* __restrict__ csre) {
  unsigned e = blockIdx.x * blockDim.x + threadIdx.x;
  if (e < N_EDGES) {
    int d = dst[e];
    int pos = row[d] + atomicAdd(&cnt[d], 1);
    csrs[pos] = src[e];
    csre[pos] = (int)e;
  }
}

// ---------------- fused per-node edge phase (MFMA for et) ----------------
// One block (128 thr = 2 waves) per destination node. Per CH=16 CSR slots:
//   A-frag: rbf rows loaded straight from global (f32->bf16) per lane
//   et tile [16][128] = rbf[16][32] @ Wcomb^T via 4 mfma_16x16x32_bf16/wave
//   (B-frags of WcombB are loop-invariant registers)
//   spill et tile to LDS, then per-edge scalar phase:
//   u = leaky(xl[src]+xr[d]+et); logit = 16-lane reduce(u*att); p=exp
//   den += p; S += p*xl[src]; etacc += et  (mean(rbf)@Wcomb == mean(et))
// Self-loop uses etacc/deg. No atomics, no materialized p/denom/acc.
__global__ __launch_bounds__(128) void k_node(
    const float* __restrict__ XLR, const float* __restrict__ rbf,
    const int* __restrict__ csrs, const int* __restrict__ csre,
    const int* __restrict__ row, const unsigned short* __restrict__ WcombB,
    const float* __restrict__ att, const float* __restrict__ bias,
    unsigned short* __restrict__ accb) {
  __shared__ __align__(16) float et_s[CH][132];  // +4 pad: writes 2-way, reads 2-way
  __shared__ int src_s[CH];
  __shared__ int eid_s[CH];
  const int tid = threadIdx.x;
  const int lane = tid & 63;
  const int wv = tid >> 6;       // 0,1
  const int n0 = lane & 15;      // edge-row index for A-frag / out-col for B
  const int q = lane >> 4;       // k-chunk / out-row quad
  const int wcol = wv << 6;
  const unsigned n = blockIdx.x;

  const float att_r = att[tid];
  const int off = row[n], end = row[n + 1];
  const float xl_d = XLR[(n << 8) + tid];
  const float xr_d = XLR[(n << 8) + 128 + tid];

  // loop-invariant B-frags: WcombB[128][32] bf16, this wave's 64 output cols
  short8 bfr[4];
#pragma unroll
  for (int j = 0; j < 4; ++j)
    bfr[j] = *(const short8*)(WcombB + (wcol + j * 16 + n0) * 32 + (q << 3));

  float S = 0.f, den = 0.f, etacc = 0.f;

  for (int c0 = off; c0 < end; c0 += CH) {
    const int cnt = min(CH, end - c0);
    __syncthreads();  // et_s/src_s reuse vs previous chunk readers
    if (tid < cnt) { src_s[tid] = csrs[c0 + tid]; eid_s[tid] = csre[c0 + tid]; }
    __syncthreads();
    // A-frag: edge row n0, k-elems q*8..q*8+7, from global (zero-fill pad rows)
    short8 af = (short8)0;
    if (n0 < cnt) {
      const float* rp = rbf + (size_t)(unsigned)eid_s[n0] * 32 + (q << 3);
      float4 v0 = ((const float4*)rp)[0];
      float4 v1 = ((const float4*)rp)[1];
      af[0] = (short)f2bf(v0.x); af[1] = (short)f2bf(v0.y);
      af[2] = (short)f2bf(v0.z); af[3] = (short)f2bf(v0.w);
      af[4] = (short)f2bf(v1.x); af[5] = (short)f2bf(v1.y);
      af[6] = (short)f2bf(v1.z); af[7] = (short)f2bf(v1.w);
    }
    float4v c[4];
#pragma unroll
    for (int j = 0; j < 4; ++j)
      c[j] = __builtin_amdgcn_mfma_f32_16x16x32_bf16(af, bfr[j], (float4v)(0.f), 0, 0, 0);
#pragma unroll
    for (int j = 0; j < 4; ++j)
#pragma unroll
      for (int r = 0; r < 4; ++r)
        et_s[(q << 2) + r][wcol + j * 16 + n0] = c[j][r];
    __syncthreads();
#pragma unroll 2
    for (int i = 0; i < cnt; ++i) {
      const unsigned s = (unsigned)src_s[i];
      const float et = et_s[i][tid];
      const float xls = XLR[(s << 8) + tid];
      float u = xls + xr_d + et;
      u = (u > 0.f) ? u : 0.2f * u;
      float r = u * att_r;
      r += __shfl_xor(r, 1);
      r += __shfl_xor(r, 2);
      r += __shfl_xor(r, 4);
      r += __shfl_xor(r, 8);
      const float p = __expf(r);
      den += p;
      S += p * xls;
      etacc += et;
    }
  }

  // self-loop: et = mean of incoming et rows (linearity of rbf@Wcomb)
  const float inv = 1.f / fmaxf((float)(end - off), 1.f);
  float u = xl_d + xr_d + etacc * inv;
  u = (u > 0.f) ? u : 0.2f * u;
  float r = u * att_r;
  r += __shfl_xor(r, 1);
  r += __shfl_xor(r, 2);
  r += __shfl_xor(r, 4);
  r += __shfl_xor(r, 8);
  const float p = __expf(r);
  den += p;
  S += p * xl_d;

  const float outv = S / den + bias[tid];
  accb[((size_t)n << 7) + tid] = f2bf(outv);
}

extern "C" void kernel_launch(void* const* d_in, const int* in_sizes, int n_in,
                              void* d_out, int out_size, void* d_ws, size_t ws_size,
                              hipStream_t stream) {
  const float* x     = (const float*)d_in[0];
  const float* rbf   = (const float*)d_in[1];
  const int*   ei    = (const int*)d_in[2];
  const float* W_n2m = (const float*)d_in[4];
  const float* W_r2m = (const float*)d_in[5];
  const float* Wl    = (const float*)d_in[6];
  const float* bl    = (const float*)d_in[7];
  const float* Wr    = (const float*)d_in[8];
  const float* br    = (const float*)d_in[9];
  const float* We    = (const float*)d_in[10];
  const float* att   = (const float*)d_in[11];
  const float* bias  = (const float*)d_in[12];
  const float* W_m2n = (const float*)d_in[13];
  float* out = (float*)d_out;
  float* ws  = (float*)d_ws;

  const int* src = ei;
  const int* dst = ei + N_EDGES;

  float* XLR    = ws + OFF_XLR;
  unsigned short* xb    = (unsigned short*)(ws + OFF_XB);
  unsigned short* accb  = (unsigned short*)(ws + OFF_ACCB);
  int* csrs   = (int*)(ws + OFF_CSRS);
  int* csre   = (int*)(ws + OFF_CSRE);
  int* rowoff = (int*)(ws + OFF_ROW);
  int* cnt    = (int*)(ws + OFF_CNT);
  int* degi   = (int*)(ws + OFF_DEGI);
  int* bsums  = (int*)(ws + OFF_BSUMS);
  float* bcat   = ws + OFF_BCAT;
  unsigned short* WcombB = (unsigned short*)(ws + OFF_WCOMBB);
  unsigned short* WcatB = (unsigned short*)(ws + OFF_WCATB);
  unsigned short* Wm2nB = (unsigned short*)(ws + OFF_WM2NB);

  // 1. fold weights (+ bf16 conversions)
  k_weights<<<401, 256, 0, stream>>>(Wl, Wr, We, W_n2m, W_r2m, bl, br, W_m2n,
                                     WcatB, bcat, WcombB, Wm2nB);
  // 2. x -> bf16
  k_convx<<<2048, 256, 0, stream>>>(x, xb, (unsigned)(N_NODES * 256 / 4));
  // 3. XLR = x @ [Wl@W_n2m ; Wr@W_n2m]^T + [bl|br]   (bf16 MFMA)
  gemm_mfma<true><<<dim3(M_PAD / 128, 2), 256, 0, stream>>>(
      xb, WcatB, bcat, XLR, N_NODES, 256, 256);
  // 4. CSR build: zero cnt+degi (contiguous 200,000 ints), hist, scan, scatter
  k_zero<<<196, 256, 0, stream>>>(ws + OFF_CNT, 50000);
  k_hist<<<N_EDGES / 256, 256, 0, stream>>>(dst, degi);
  k_scan1<<<SCAN_NB, 1024, 0, stream>>>(degi, rowoff, bsums);
  k_scan2<<<1, 128, 0, stream>>>(bsums);
  k_scan3<<<SCAN_NB, 1024, 0, stream>>>(rowoff, bsums);
  k_scatter<<<N_EDGES / 256, 256, 0, stream>>>(src, dst, rowoff, cnt, csrs, csre);
  // 5. fused edge phase: one block per node, MFMA et, no atomics
  k_node<<<N_NODES, 128, 0, stream>>>(XLR, rbf, csrs, csre, rowoff, WcombB,
                                      att, bias, accb);
  // 6. out = acc @ W_m2n^T  (bf16 MFMA)
  gemm_mfma<false><<<dim3(M_PAD / 128, 2), 256, 0, stream>>>(
      accb, Wm2nB, nullptr, out, N_NODES, 256, 128);
}